// Round 6
// baseline (140.305 us; speedup 1.0000x reference)
//
#include <hip/hip_runtime.h>

typedef float v2f __attribute__((ext_vector_type(2)));

#define HW      1024   // H*W = BN channel count (spatial positions)
#define NLAYERS 30

// ---------------------------------------------------------------------------
// DPP wave64 sum (pure VALU, no LDS pipe), result broadcast via readlane.
// ---------------------------------------------------------------------------
template <int CTRL, int RMASK>
__device__ __forceinline__ float dpp_add(float x) {
    int t = __builtin_amdgcn_update_dpp(0, __builtin_bit_cast(int, x),
                                        CTRL, RMASK, 0xf, true);
    return x + __builtin_bit_cast(float, t);
}
__device__ __forceinline__ float wave_sum_bcast(float x) {
    x = dpp_add<0x111, 0xf>(x);   // row_shr:1
    x = dpp_add<0x112, 0xf>(x);   // row_shr:2
    x = dpp_add<0x114, 0xf>(x);   // row_shr:4
    x = dpp_add<0x118, 0xf>(x);   // row_shr:8
    x = dpp_add<0x142, 0xa>(x);   // row_bcast15 -> rows 1,3
    x = dpp_add<0x143, 0xc>(x);   // row_bcast31 -> rows 2,3 (lane63 = total)
    return __builtin_bit_cast(float,
        __builtin_amdgcn_readlane(__builtin_bit_cast(int, x), 63));
}

// ---------------------------------------------------------------------------
// ONE WAVE per BN channel p: 64 lanes x 64 elements = the whole 4096-element
// reduction domain lives in this wave's registers. The 30-layer loop has NO
// barrier and NO LDS round-trip — BN stats are 2 DPP chains + readlane.
// Element map: e = t + 64c + 256j (c=0..3, j=0..15) -> m-index = t + 64c,
// 4 scalar m's per lane per layer (LDS, prefetched one layer ahead).
// Epilogue algebra (avoids storing z[64]):
//   dt*clamp(g*z+bb,0,6) = med3(gd*m*x1 + (gd*y + bd), 0, 6dt), gd=g*dt
//   y' = (1-dt)*y + that.
// XCD swizzle keeps each 64B x/out line on one XCD's L2 (R4: 220->25 MB).
// ---------------------------------------------------------------------------
__global__ __launch_bounds__(64) void ode_fused(const float* __restrict__ x,
                                                const float* __restrict__ delta_t,
                                                const float* __restrict__ matrices,
                                                const float* __restrict__ gamma,
                                                const float* __restrict__ beta,
                                                float* __restrict__ out) {
    const int bid = blockIdx.x;
    const int p   = ((bid & 7) << 7) | (bid >> 3);   // XCD-contiguous channel
    const int t   = threadIdx.x;                     // lane 0..63

    __shared__ float smat[(NLAYERS + 1) * 256];      // +pad row: uncond prefetch
    __shared__ float sdt[NLAYERS + 1];

#pragma unroll
    for (int i = 0; i < NLAYERS * 4; ++i)            // 30 KB, L3-served
        smat[i * 64 + t] = matrices[i * 64 + t];
    if (t < NLAYERS)
        sdt[t] = __builtin_amdgcn_fmed3f(delta_t[t], 0.0f, 6.0f);

    // Gather column p: 64 loads/lane, stride 4 KB (one XCD's L2 per line).
    v2f x1[4][8], y[4][8];
#pragma unroll
    for (int c = 0; c < 4; ++c)
#pragma unroll
        for (int j = 0; j < 8; ++j) {
            x1[c][j].x = x[(size_t)(t + 64 * c + 256 * j) * HW + p];
            x1[c][j].y = x[(size_t)(t + 64 * c + 256 * j + 2048) * HW + p];
            y[c][j] = x1[c][j];
        }

    const float gp = gamma[p];
    const float bp = beta[p];

    __syncthreads();   // once: make staged LDS visible (single-wave block)

    float mcur[4];
#pragma unroll
    for (int c = 0; c < 4; ++c) mcur[c] = smat[t + 64 * c];
    float dtl = sdt[0];

    for (int l = 0; l < NLAYERS; ++l) {
        // z = fma(m, x1, y); accumulate (sum, sumsq) in 4 independent chains
        v2f sacc[4], qacc[4];
#pragma unroll
        for (int i = 0; i < 4; ++i) { sacc[i] = (v2f){0.f, 0.f}; qacc[i] = (v2f){0.f, 0.f}; }
#pragma unroll
        for (int c = 0; c < 4; ++c) {
            const v2f m2 = {mcur[c], mcur[c]};
#pragma unroll
            for (int j = 0; j < 8; ++j) {
                const v2f z = __builtin_elementwise_fma(m2, x1[c][j], y[c][j]);
                sacc[j & 3] += z;
                qacc[j & 3] = __builtin_elementwise_fma(z, z, qacc[j & 3]);
            }
        }
        // Prefetch next layer's params; ds_read latency hides under DPP+epi.
        float mnxt[4];
#pragma unroll
        for (int c = 0; c < 4; ++c) mnxt[c] = smat[(l + 1) * 256 + t + 64 * c];
        const float dtn = sdt[l + 1];

        const v2f sv = (sacc[0] + sacc[1]) + (sacc[2] + sacc[3]);
        const v2f qv = (qacc[0] + qacc[1]) + (qacc[2] + qacc[3]);
        const float S = wave_sum_bcast(sv.x + sv.y);
        const float Q = wave_sum_bcast(qv.x + qv.y);

        const float mean = S * (1.0f / 4096.0f);
        const float var  = fmaf(-mean, mean, Q * (1.0f / 4096.0f));
        const float rstd = rsqrtf(var + 1e-5f);
        const float g    = gp * rstd;
        const float bb   = fmaf(-mean, g, bp);
        const float gd = g * dtl, bd = bb * dtl, sixdt = 6.0f * dtl;
        const float om = 1.0f - dtl;
        const v2f gd2 = {gd, gd}, bd2 = {bd, bd}, om2 = {om, om};
#pragma unroll
        for (int c = 0; c < 4; ++c) {
            const float gm = gd * mcur[c];
            const v2f gm2 = {gm, gm};
#pragma unroll
            for (int j = 0; j < 8; ++j) {
                v2f a = __builtin_elementwise_fma(y[c][j], gd2, bd2);  // gd*y+bd
                a = __builtin_elementwise_fma(x1[c][j], gm2, a);       // +gd*m*x1
                a.x = __builtin_amdgcn_fmed3f(a.x, 0.0f, sixdt);       // clamp
                a.y = __builtin_amdgcn_fmed3f(a.y, 0.0f, sixdt);
                y[c][j] = __builtin_elementwise_fma(om2, y[c][j], a);  // (1-dt)y+.
            }
        }
#pragma unroll
        for (int c = 0; c < 4; ++c) mcur[c] = mnxt[c];
        dtl = dtn;
    }

    // Scatter out = y + x1; partial lines merge in the owning XCD's L2.
#pragma unroll
    for (int c = 0; c < 4; ++c)
#pragma unroll
        for (int j = 0; j < 8; ++j) {
            out[(size_t)(t + 64 * c + 256 * j) * HW + p]        = y[c][j].x + x1[c][j].x;
            out[(size_t)(t + 64 * c + 256 * j + 2048) * HW + p] = y[c][j].y + x1[c][j].y;
        }
}

extern "C" void kernel_launch(void* const* d_in, const int* in_sizes, int n_in,
                              void* d_out, int out_size, void* d_ws, size_t ws_size,
                              hipStream_t stream) {
    const float* x        = (const float*)d_in[0];   // [16,256,32,32]
    const float* delta_t  = (const float*)d_in[1];   // [30,1]
    const float* matrices = (const float*)d_in[2];   // [30,1,1,16,16]
    const float* gamma    = (const float*)d_in[3];   // [1024]
    const float* beta     = (const float*)d_in[4];   // [1024]
    float* out = (float*)d_out;

    ode_fused<<<dim3(HW), dim3(64), 0, stream>>>(x, delta_t, matrices, gamma, beta, out);
}

// Round 7
// 123.282 us; speedup vs baseline: 1.1381x; 1.1381x over previous
//
#include <hip/hip_runtime.h>

typedef float v2f __attribute__((ext_vector_type(2)));

#define HW      1024   // H*W = BN channel count
#define NLAYERS 30
#define TPB     512    // 8 waves; block owns TWO channels (pA, pB=pA+1)

// ---------------------------------------------------------------------------
// DPP wave64 sum on a packed v2f (reduces .x and .y independently).
// GCNDPPCombine fuses update_dpp+add into one v_add_f32_dpp per level.
// ---------------------------------------------------------------------------
template <int CTRL, int RMASK>
__device__ __forceinline__ v2f dpp_add2(v2f x) {
    int a = __builtin_amdgcn_update_dpp(0, __builtin_bit_cast(int, x.x),
                                        CTRL, RMASK, 0xf, true);
    int b = __builtin_amdgcn_update_dpp(0, __builtin_bit_cast(int, x.y),
                                        CTRL, RMASK, 0xf, true);
    v2f r;
    r.x = x.x + __builtin_bit_cast(float, a);
    r.y = x.y + __builtin_bit_cast(float, b);
    return r;
}
__device__ __forceinline__ v2f wave_sum64_v2(v2f x) {
    x = dpp_add2<0x111, 0xf>(x);   // row_shr:1
    x = dpp_add2<0x112, 0xf>(x);   // row_shr:2
    x = dpp_add2<0x114, 0xf>(x);   // row_shr:4
    x = dpp_add2<0x118, 0xf>(x);   // row_shr:8
    x = dpp_add2<0x142, 0xa>(x);   // row_bcast15 -> rows 1,3
    x = dpp_add2<0x143, 0xc>(x);   // row_bcast31 -> rows 2,3
    return x;                      // lane 63 holds both totals
}

// ---------------------------------------------------------------------------
// Fused 30-layer ODE, TWO channels per block packed in v2f halves.
// m[l,c] is channel-independent -> one scalar m per thread per layer drives
// both channels. Thread t owns elems e = t + 512k (k=0..7) of each channel;
// c = e mod 256 = t & 255. Stats (sum,sumsq) for BOTH channels come from the
// same packed accumulator chain; one DPP reduction + ONE barrier per layer
// serves both. gamma/beta/mean/var/rstd stay packed (.x=pA, .y=pB).
// XCD swizzle: 64 consecutive blocks (same bid&7) own a contiguous 128-wide
// p range -> each 64B x/out line is fetched/written by one XCD L2 (R4 fix).
// ---------------------------------------------------------------------------
__global__ __launch_bounds__(TPB) void ode_fused(const float* __restrict__ x,
                                                 const float* __restrict__ delta_t,
                                                 const float* __restrict__ matrices,
                                                 const float* __restrict__ gamma,
                                                 const float* __restrict__ beta,
                                                 float* __restrict__ out) {
    const int bid  = blockIdx.x;                         // 0..511
    const int pA   = ((bid & 7) << 7) | ((bid >> 3) << 1);
    const int t    = threadIdx.x;                        // 0..511
    const int c    = t & 255;
    const int wid  = t >> 6;                             // 0..7
    const int lane = t & 63;

    __shared__ float smat[(NLAYERS + 1) * 256];          // +pad: uncond prefetch
    __shared__ float sdt[NLAYERS + 1];
    __shared__ __align__(16) float4 red[2][8];           // [parity][wave]=(sA,sB,qA,qB)

    for (int i = t; i < NLAYERS * 256; i += TPB)
        smat[i] = matrices[i];
    if (t < NLAYERS) sdt[t] = __builtin_amdgcn_fmed3f(delta_t[t], 0.0f, 6.0f);
    if (t == 0) sdt[NLAYERS] = 0.0f;

    // Gather: one float2 per element covers BOTH channels (pA, pA+1).
    const float2* __restrict__ xp = (const float2*)(x + pA);
    v2f x1[8], y[8];
#pragma unroll
    for (int k = 0; k < 8; ++k) {
        const float2 v = xp[(size_t)(t + 512 * k) * (HW / 2)];
        x1[k].x = v.x; x1[k].y = v.y;
        y[k] = x1[k];
    }

    const float2 gpv = *(const float2*)(gamma + pA);
    const float2 bpv = *(const float2*)(beta + pA);
    const v2f gp2 = {gpv.x, gpv.y};
    const v2f bp2 = {bpv.x, bpv.y};

    __syncthreads();   // staged params visible
    float m_cur = smat[c];
    float dtl   = sdt[0];

    for (int l = 0; l < NLAYERS; ++l) {
        const v2f m2  = {m_cur, m_cur};
        const v2f dt2 = {dtl, dtl};
        const v2f om2 = {1.0f - dtl, 1.0f - dtl};

        // z = fma(m, x1, y); packed (A,B) sums in 2 independent chains each
        v2f z[8];
        v2f sA = {0.f, 0.f}, sB = {0.f, 0.f};
        v2f qA = {0.f, 0.f}, qB = {0.f, 0.f};
#pragma unroll
        for (int k = 0; k < 8; k += 2) {
            z[k]     = __builtin_elementwise_fma(m2, x1[k], y[k]);
            z[k + 1] = __builtin_elementwise_fma(m2, x1[k + 1], y[k + 1]);
            sA += z[k];
            sB += z[k + 1];
            qA = __builtin_elementwise_fma(z[k], z[k], qA);
            qB = __builtin_elementwise_fma(z[k + 1], z[k + 1], qB);
        }
        // Off critical path: pre-scale y by (1-dt) while the reduction runs.
#pragma unroll
        for (int k = 0; k < 8; ++k) y[k] *= om2;

        const v2f sv = wave_sum64_v2(sA + sB);   // (SA, SB) in lane 63
        const v2f qv = wave_sum64_v2(qA + qB);   // (QA, QB) in lane 63

        const int par = l & 1;
        if (lane == 63) {
            float4 w; w.x = sv.x; w.y = sv.y; w.z = qv.x; w.w = qv.y;
            red[par][wid] = w;
        }
        m_cur = smat[(l + 1) * 256 + c];         // prefetch; drains w/ barrier
        const float dtn = sdt[l + 1];
        __syncthreads();

        // Combine 8 per-wave partials (broadcast reads, conflict-free).
        float4 acc = red[par][0];
#pragma unroll
        for (int w = 1; w < 8; ++w) {
            const float4 r = red[par][w];
            acc.x += r.x; acc.y += r.y; acc.z += r.z; acc.w += r.w;
        }
        const v2f S = {acc.x, acc.y};            // (SA, SB)
        const v2f Q = {acc.z, acc.w};            // (QA, QB)

        const v2f mean = S * (1.0f / 4096.0f);
        v2f var = Q * (1.0f / 4096.0f) - mean * mean;
        v2f rstd; rstd.x = rsqrtf(var.x + 1e-5f); rstd.y = rsqrtf(var.y + 1e-5f);
        const v2f g  = gp2 * rstd;               // fold gamma into scale
        const v2f bb = bp2 - mean * g;           // fold mean into bias
#pragma unroll
        for (int k = 0; k < 8; ++k) {
            v2f a = __builtin_elementwise_fma(z[k], g, bb);
            a.x = __builtin_amdgcn_fmed3f(a.x, 0.0f, 6.0f);
            a.y = __builtin_amdgcn_fmed3f(a.y, 0.0f, 6.0f);
            y[k] = __builtin_elementwise_fma(dt2, a, y[k]);  // y=(1-dt)y+dt*a
        }
        dtl = dtn;
    }

    // Scatter out = y + x1 as float2 (both channels); lines merge in XCD L2.
    float2* __restrict__ outp = (float2*)(out + pA);
#pragma unroll
    for (int k = 0; k < 8; ++k) {
        float2 w;
        w.x = y[k].x + x1[k].x;
        w.y = y[k].y + x1[k].y;
        outp[(size_t)(t + 512 * k) * (HW / 2)] = w;
    }
}

extern "C" void kernel_launch(void* const* d_in, const int* in_sizes, int n_in,
                              void* d_out, int out_size, void* d_ws, size_t ws_size,
                              hipStream_t stream) {
    const float* x        = (const float*)d_in[0];   // [16,256,32,32]
    const float* delta_t  = (const float*)d_in[1];   // [30,1]
    const float* matrices = (const float*)d_in[2];   // [30,1,1,16,16]
    const float* gamma    = (const float*)d_in[3];   // [1024]
    const float* beta     = (const float*)d_in[4];   // [1024]
    float* out = (float*)d_out;

    ode_fused<<<dim3(HW / 2), dim3(TPB), 0, stream>>>(x, delta_t, matrices,
                                                      gamma, beta, out);
}